// Round 1
// baseline (183.525 us; speedup 1.0000x reference)
//
#include <hip/hip_runtime.h>

// RoIAlign1D: feat [B,T,D] f32, spans [B,K,2] i32, lengths [B] i32 -> out [B,K,P,D] f32
// B=16, T=4096, D=512, K=64, P=16

constexpr int B  = 16;
constexpr int T  = 4096;
constexpr int D  = 512;
constexpr int K  = 64;
constexpr int P  = 16;
constexpr int D4 = D / 4;  // 128 float4 slots per row

typedef float f32x4 __attribute__((ext_vector_type(4)));

// One block per RoI (b,k): 256 threads = 2 p-rows per iteration, 8 unrolled
// iterations. Span/length loads amortized 16x vs the per-row-block version;
// each thread carries 8 independent load-pairs for latency hiding.
__global__ __launch_bounds__(256) void roialign1d_kernel(
    const float* __restrict__ feat,
    const int* __restrict__ spans,
    const int* __restrict__ lengths,
    float* __restrict__ out) {

    const int bk = blockIdx.x;        // [0, B*K)
    const int b  = bk >> 6;           // K = 64

    const int Lm1 = lengths[b] - 1;
    int s0 = spans[bk * 2 + 0];
    int s1 = spans[bk * 2 + 1];
    s0 = min(max(s0, 0), Lm1);
    s1 = min(max(s1, 0), Lm1);
    const int s      = min(s0, s1);
    const int seglen = max(s0, s1) - s + 1;
    const int   smax  = seglen - 1;
    const float segm1 = (float)smax;

    const int tid  = threadIdx.x;
    const int half = tid >> 7;        // which p of the pair (0/1)
    const int d    = tid & (D4 - 1);  // float4 slot within the row

    const f32x4* __restrict__ fb = (const f32x4*)feat + (size_t)b * T * D4;
    f32x4* __restrict__ ob       = (f32x4*)out + (size_t)bk * P * D4;

#pragma unroll
    for (int i = 0; i < P / 2; ++i) {
        const int p = i * 2 + half;
        // Exact fp32 replication of the reference linspace math.
        // (float)p / 15.0f constant-folds per unrolled iteration.
        const float t   = (float)p / 15.0f;
        const float idx = t * segm1;
        const int   i0  = min((int)floorf(idx), smax);
        const int   i1  = min(i0 + 1, smax);
        const float w   = idx - (float)i0;   // after the min, per reference
        const float wm  = 1.0f - w;

        const f32x4 a = fb[(size_t)(s + i0) * D4 + d];
        const f32x4 c = fb[(size_t)(s + i1) * D4 + d];
        const f32x4 r = wm * a + w * c;

        // Output is write-once: bypass cache, keep L2/L3 for feat-row reuse.
        __builtin_nontemporal_store(r, &ob[p * D4 + d]);
    }
}

extern "C" void kernel_launch(void* const* d_in, const int* in_sizes, int n_in,
                              void* d_out, int out_size, void* d_ws, size_t ws_size,
                              hipStream_t stream) {
    const float* feat    = (const float*)d_in[0];
    const int*   spans   = (const int*)d_in[1];
    const int*   lengths = (const int*)d_in[2];
    float*       out     = (float*)d_out;

    roialign1d_kernel<<<B * K, 256, 0, stream>>>(feat, spans, lengths, out);
}